// Round 4
// baseline (257.313 us; speedup 1.0000x reference)
//
#include <hip/hip_runtime.h>
#include <cstdint>
#include <cstddef>

#define H1DIM 512
#define H2DIM 256
#define DNODE 1280
#define NPACK 1024   // GEMM1 packed output width (XWt | XWb), bf16
#define APAD  40     // LDS row stride in ushorts: 80B keeps b128 reads 16B-aligned, 2-way banks
#define BM    64     // M-tile: 64 rows -> GEMM2 1563 blocks (3.05 sched waves, no tail),
                     // GEMM1 628 blocks (balanced), acc VGPR halved vs 128-row tile

typedef __attribute__((ext_vector_type(8))) short short8v;
typedef __attribute__((ext_vector_type(4))) float f32x4;
typedef __attribute__((ext_vector_type(4))) unsigned short us4;

__device__ __forceinline__ unsigned short f2bf(float f) {
    unsigned int u = __builtin_bit_cast(unsigned int, f);
    u += 0x7fffu + ((u >> 16) & 1u);   // RNE
    return (unsigned short)(u >> 16);
}
__device__ __forceinline__ float bf2f(unsigned short h) {
    unsigned int u = ((unsigned int)h) << 16;
    return __builtin_bit_cast(float, u);
}

// ---------------- CSR build ----------------
__global__ void hist_k(const int* __restrict__ e1, int* __restrict__ hist, int E) {
    int e = blockIdx.x * 256 + threadIdx.x;
    if (e < E) atomicAdd(&hist[e1[e]], 1);
}
__global__ __launch_bounds__(1024) void scan_dinv_k(
    const int* __restrict__ hist, int* __restrict__ off, int* __restrict__ cursor,
    float* __restrict__ dinv, int N)
{
    __shared__ int part[1024];
    const int t = threadIdx.x;
    const int per = (N + 1023) / 1024;
    const int base = t * per;
    int s = 0;
    for (int i = 0; i < per; ++i) { int b = base + i; if (b < N) s += hist[b]; }
    part[t] = s;
    __syncthreads();
    for (int d = 1; d < 1024; d <<= 1) {
        int v = (t >= d) ? part[t - d] : 0;
        __syncthreads();
        part[t] += v;
        __syncthreads();
    }
    int run = (t == 0) ? 0 : part[t - 1];
    for (int i = 0; i < per; ++i) {
        int b = base + i;
        if (b < N) {
            int h = hist[b];
            off[b] = run;
            run += h;
            cursor[b] = 0;
            dinv[b] = rsqrtf(1.0f + (float)h);
        }
    }
    if (t == 1023) off[N] = run;
}
__global__ void fill_k(const int* __restrict__ e0, const int* __restrict__ e1,
                       const int* __restrict__ off, int* __restrict__ cursor,
                       int* __restrict__ srcs, int E) {
    int e = blockIdx.x * 256 + threadIdx.x;
    if (e < E) {
        int t = e1[e];
        int p = off[t] + atomicAdd(&cursor[t], 1);
        srcs[p] = e0[e];
    }
}

// ---------------- prep ----------------
__global__ void cvt_x_k(const float* __restrict__ src, unsigned short* __restrict__ dst, int n) {
    int i = blockIdx.x * 256 + threadIdx.x;
    if (i * 4 < n) {
        f32x4 v = *reinterpret_cast<const f32x4*>(src + (size_t)i * 4);
        us4 o;
        o[0] = f2bf(v.x); o[1] = f2bf(v.y); o[2] = f2bf(v.z); o[3] = f2bf(v.w);
        *reinterpret_cast<us4*>(dst + (size_t)i * 4) = o;
    }
}

__global__ __launch_bounds__(256) void transpose_cvt_k(
    const float* __restrict__ src, unsigned short* __restrict__ dst, int ldsrc, int lddst)
{
    __shared__ float tile[32][33];
    const int c0 = blockIdx.x * 32;
    const int r0 = blockIdx.y * 32;
    const int tx = threadIdx.x & 31;
    const int ty = threadIdx.x >> 5;
#pragma unroll
    for (int rr = ty; rr < 32; rr += 8)
        tile[rr][tx] = src[(size_t)(r0 + rr) * ldsrc + c0 + tx];
    __syncthreads();
#pragma unroll
    for (int rr = ty; rr < 32; rr += 8)
        dst[(size_t)(c0 + rr) * lddst + r0 + tx] = f2bf(tile[tx][rr]);
}

// ---------------- unified bf16 MFMA GEMM, tile 64x256, BK=32, 512 thr (8 waves 2Mx4N) ----
// Wave tile 32x64 (acc[2][4] = 32 VGPR). Double-buffered LDS, ONE barrier per K-step.
// MODE 0 (GEMM1): A = Ab bf16 [M][K]; C = Cb bf16 [M][NPACK], 4 n-tiles, XCD swizzle.
// MODE 1 (GEMM2): K=512, single n-tile (256). A row gm:
//     gm < Nn : out1b[gm] (post-relu bf16)
//     else    : relu(b1 + XWb16[e0[gm]][0:512] + XWb16[e1[gm]][512:1024])  (bf16 gather)
//   Outputs: h2f rows < Nn (fp32), pre_raw[gm] = relu(h2+b2)·Wl for gm >= Nn.
template <int MODE>
__global__ __launch_bounds__(512, 4) void gemm_u_k(
    const unsigned short* __restrict__ Ab,
    const unsigned short* __restrict__ Bt,
    unsigned short* __restrict__ Cb,
    const unsigned short* __restrict__ out1b,
    const unsigned short* __restrict__ XWb16,
    const float* __restrict__ b1,
    const float* __restrict__ b2,
    const float* __restrict__ Wl,
    const int* __restrict__ e0, const int* __restrict__ e1,
    float* __restrict__ h2f, float* __restrict__ pre_raw,
    int M, int K, int Nn, int nwg)
{
    __shared__ unsigned short As[2][BM * APAD];
    __shared__ unsigned short Bs[2][256 * APAD];
    __shared__ unsigned short b1h[H1DIM];   // b1 as bf16 (biases are tiny vs 0.02 threshold)
    __shared__ float preacc[BM];

    const int tid  = threadIdx.x;
    const int lane = tid & 63;
    const int w    = tid >> 6;
    const int wm   = w >> 2, wn = w & 3;

    int mb, n0;
    if (MODE == 0) {
        // bijective XCD swizzle (m204): consecutive logical tiles land on one XCD
        const int q = nwg >> 3, r = nwg & 7;
        const int xcd = blockIdx.x & 7;
        const int base = (xcd < r) ? xcd * (q + 1) : r * (q + 1) + (xcd - r) * q;
        const int wg = base + (blockIdx.x >> 3);
        mb = wg >> 2;             // n fastest: 4 n-tiles share A rows in L2
        n0 = (wg & 3) << 8;
    } else {
        mb = blockIdx.x;
        n0 = 0;
    }
    const int m0 = mb * BM;

    if (MODE == 1) {
        if (tid < BM) preacc[tid] = 0.f;
        b1h[tid] = f2bf(b1[tid]);   // 512 threads == H1DIM
    }

    // staging: A 64x32 by threads 0..255 (8 bf16/thr), B 256x32 by all (16 bf16/thr)
    const bool astage = tid < 256;
    const int sa_r = tid >> 2, sa_k = (tid & 3) << 3;     // valid when astage
    const int sb_r = tid >> 1, sb_k = (tid & 1) << 4;
    const int gma  = m0 + sa_r;
    const bool aval = astage && (gma < M);

    const unsigned short* bsrc = Bt + (size_t)(n0 + sb_r) * K + sb_k;
    const unsigned short* s1 = nullptr;
    const unsigned short* s2 = nullptr;
    bool dual = false;
    if (MODE == 0) {
        if (aval) s1 = Ab + (size_t)gma * K + sa_k;
    } else if (aval) {
        if (gma < Nn) {
            s1 = out1b + (size_t)gma * H1DIM + sa_k;
        } else {
            s1 = XWb16 + (size_t)e0[gma] * NPACK + sa_k;
            s2 = XWb16 + (size_t)e1[gma] * NPACK + H1DIM + sa_k;
            dual = true;
        }
    }
    if (MODE == 1) __syncthreads();   // b1h/preacc ready

    f32x4 acc[2][4];
#pragma unroll
    for (int i = 0; i < 2; ++i)
#pragma unroll
        for (int j = 0; j < 4; ++j) acc[i][j] = f32x4{0.f, 0.f, 0.f, 0.f};

    short8v ab1, ab2, bb0, bb1;

    auto load_tile = [&](int k0) {
        bb0 = *reinterpret_cast<const short8v*>(bsrc + k0);
        bb1 = *reinterpret_cast<const short8v*>(bsrc + k0 + 8);
        if (aval) {
            ab1 = *reinterpret_cast<const short8v*>(s1 + k0);
            if (MODE == 1 && dual) ab2 = *reinterpret_cast<const short8v*>(s2 + k0);
        }
    };
    auto write_lds = [&](int buf, int k0) {
        *reinterpret_cast<short8v*>(&Bs[buf][sb_r * APAD + sb_k])     = bb0;
        *reinterpret_cast<short8v*>(&Bs[buf][sb_r * APAD + sb_k + 8]) = bb1;
        if (astage) {
            short8v av;
            if (!aval) {
                av = short8v{0,0,0,0,0,0,0,0};
            } else if (MODE == 0 || !dual) {
                av = ab1;   // bf16 passthrough (xb / out1b already converted)
            } else {
#pragma unroll
                for (int ii = 0; ii < 8; ++ii) {
                    float v = bf2f((unsigned short)ab1[ii]) + bf2f((unsigned short)ab2[ii])
                            + bf2f(b1h[k0 + sa_k + ii]);
                    v = fmaxf(v, 0.f);
                    av[ii] = (short)f2bf(v);
                }
            }
            *reinterpret_cast<short8v*>(&As[buf][sa_r * APAD + sa_k]) = av;
        }
    };

    const int arow = wm * 32 + (lane & 15);
    const int brow = wn * 64 + (lane & 15);
    const int kq   = (lane >> 4) << 3;

    load_tile(0);
    int buf = 0;
    for (int k0 = 0; k0 < K; k0 += 32) {
        write_lds(buf, k0);
        __syncthreads();                     // writes to buf visible; iter i-1 reads of buf^1 done
        if (k0 + 32 < K) load_tile(k0 + 32); // global loads overlap this step's LDS reads + MFMA

        const unsigned short* as = As[buf];
        const unsigned short* bs = Bs[buf];
        short8v af[2], bfq[4];
#pragma unroll
        for (int i = 0; i < 2; ++i)
            af[i] = *reinterpret_cast<const short8v*>(&as[(arow + i * 16) * APAD + kq]);
#pragma unroll
        for (int j = 0; j < 4; ++j)
            bfq[j] = *reinterpret_cast<const short8v*>(&bs[(brow + j * 16) * APAD + kq]);
#pragma unroll
        for (int i = 0; i < 2; ++i)
#pragma unroll
            for (int j = 0; j < 4; ++j)
                acc[i][j] = __builtin_amdgcn_mfma_f32_16x16x32_bf16(af[i], bfq[j], acc[i][j], 0, 0, 0);
        buf ^= 1;                            // next step writes other buffer: no 2nd barrier
    }

    const int crow0 = m0 + wm * 32 + ((lane >> 4) << 2);
    if (MODE == 0) {
        const int ccol = n0 + wn * 64 + (lane & 15);
#pragma unroll
        for (int i = 0; i < 2; ++i)
#pragma unroll
            for (int q = 0; q < 4; ++q) {
                const int row = crow0 + i * 16 + q;
                if (row < M) {
#pragma unroll
                    for (int j = 0; j < 4; ++j)
                        Cb[(size_t)row * NPACK + ccol + j * 16] = f2bf(acc[i][j][q]);
                }
            }
    } else {
        // fused pre = relu(h2 + b2) · Wl  (per-row scalar); b2/Wl direct from L2 (zeros in test)
        const int cbase = wn * 64 + (lane & 15);
        float b2v[4], wlv[4];
#pragma unroll
        for (int j = 0; j < 4; ++j) { b2v[j] = b2[cbase + j * 16]; wlv[j] = Wl[cbase + j * 16]; }
#pragma unroll
        for (int i = 0; i < 2; ++i)
#pragma unroll
            for (int q = 0; q < 4; ++q) {
                float v = 0.f;
#pragma unroll
                for (int j = 0; j < 4; ++j)
                    v += fmaxf(acc[i][j][q] + b2v[j], 0.f) * wlv[j];
                v += __shfl_xor(v, 1, 64);
                v += __shfl_xor(v, 2, 64);
                v += __shfl_xor(v, 4, 64);
                v += __shfl_xor(v, 8, 64);
                if ((lane & 15) == 0)
                    atomicAdd(&preacc[wm * 32 + i * 16 + ((lane >> 4) << 2) + q], v);
            }
        if (m0 < Nn) {
            const int ccol = wn * 64 + (lane & 15);
#pragma unroll
            for (int i = 0; i < 2; ++i)
#pragma unroll
                for (int q = 0; q < 4; ++q) {
                    const int row = crow0 + i * 16 + q;
                    if (row < Nn) {
#pragma unroll
                        for (int j = 0; j < 4; ++j)
                            h2f[(size_t)row * H2DIM + ccol + j * 16] = acc[i][j][q];
                    }
                }
        }
        __syncthreads();
        if (tid < BM) {
            const int gm = m0 + tid;
            if (gm >= Nn && gm < M) pre_raw[gm] = preacc[tid];
        }
    }
}

// ---------------- layer1: H1s[r] = (XWt[e0]+XWb[e1]) * dinv[r] (bf16 in, fp32 out) ----------------
__global__ __launch_bounds__(256) void build1_k(
    const unsigned short* __restrict__ XWb16, const float* __restrict__ dinv,
    const int* __restrict__ e0, const int* __restrict__ e1,
    float* __restrict__ H1s)
{
    const int r = blockIdx.x;
    const int a = e0[r], b = e1[r];
    const float dv = dinv[r];
    const unsigned short* pt = XWb16 + (size_t)a * NPACK;
    const unsigned short* pb = XWb16 + (size_t)b * NPACK + H1DIM;
    const int j = threadIdx.x * 2;
    const unsigned ut = *reinterpret_cast<const unsigned*>(pt + j);
    const unsigned ub = *reinterpret_cast<const unsigned*>(pb + j);
    float2 o;
    o.x = (bf2f((unsigned short)(ut & 0xffff)) + bf2f((unsigned short)(ub & 0xffff))) * dv;
    o.y = (bf2f((unsigned short)(ut >> 16))   + bf2f((unsigned short)(ub >> 16)))   * dv;
    *reinterpret_cast<float2*>(H1s + (size_t)r * H1DIM + j) = o;
}

// ---------------- CSR aggregation layer 1 -> post-relu bf16 out1 ----------------
__global__ __launch_bounds__(256) void agg1_k(
    const float* __restrict__ H1s, const int* __restrict__ off, const int* __restrict__ srcs,
    const float* __restrict__ b1, const float* __restrict__ dinv,
    unsigned short* __restrict__ out1b)
{
    const int t = blockIdx.x;
    const int j = threadIdx.x * 2;
    const int s0 = off[t], s1e = off[t + 1];
    const float dt = dinv[t];
    float2 acc = *reinterpret_cast<const float2*>(H1s + (size_t)t * H1DIM + j);
    for (int i = s0; i < s1e; ++i) {
        const float2 v = *reinterpret_cast<const float2*>(H1s + (size_t)srcs[i] * H1DIM + j);
        acc.x += v.x; acc.y += v.y;
    }
    const float ox = fmaxf(b1[j]     + dt * acc.x, 0.f);
    const float oy = fmaxf(b1[j + 1] + dt * acc.y, 0.f);
    const unsigned pk = (unsigned)f2bf(ox) | ((unsigned)f2bf(oy) << 16);
    *reinterpret_cast<unsigned*>(out1b + (size_t)t * H1DIM + j) = pk;
}

// ---------------- CSR aggregation layer 2, fused with Wl dot -> pre_low[t] ----------------
__global__ __launch_bounds__(256) void agg2_k(
    const float* __restrict__ h2f, const int* __restrict__ off, const int* __restrict__ srcs,
    const float* __restrict__ b2, const float* __restrict__ Wl,
    const float* __restrict__ dinv, float* __restrict__ pre_low)
{
    __shared__ float part[4];
    const int t = blockIdx.x;
    const int j = threadIdx.x;
    const int s0 = off[t], s1e = off[t + 1];
    const float dt = dinv[t];
    float acc = h2f[(size_t)t * H2DIM + j] * dt;
    for (int i = s0; i < s1e; ++i) {
        const int s = srcs[i];
        acc += h2f[(size_t)s * H2DIM + j] * dinv[s];
    }
    float p = fmaxf(b2[j] + dt * acc, 0.f) * Wl[j];
#pragma unroll
    for (int o = 32; o; o >>= 1) p += __shfl_down(p, o, 64);
    if ((j & 63) == 0) part[j >> 6] = p;
    __syncthreads();
    if (j == 0) pre_low[t] = part[0] + part[1] + part[2] + part[3];
}

// ---------------- final: gumbel-sigmoid + mask + kld ----------------
__global__ __launch_bounds__(256) void final2_k(
    const float* __restrict__ pre_low, const float* __restrict__ pre_raw,
    const float* __restrict__ blp, const float* __restrict__ eps,
    float* __restrict__ dout, int E, int Nn)
{
    __shared__ float part[4];
    const int i = blockIdx.x * 256 + threadIdx.x;
    float kld = 0.f;
    if (i < E) {
        const float pre = ((i < Nn) ? pre_low[i] : pre_raw[i]) + blp[0];
        const float ee = eps[i];
        const float gate = logf(ee) - log1pf(-ee) + pre;
        const float m = 1.0f / (1.0f + expf(-gate));
        dout[1 + i] = m;
        const float pos = m, neg = 1.0f - m;
        kld = pos * logf(pos * 2.0f + 1e-8f) + neg * logf(neg * 2.0f + 1e-9f);
    }
#pragma unroll
    for (int o = 32; o; o >>= 1) kld += __shfl_down(kld, o, 64);
    const int lane = threadIdx.x & 63, wv = threadIdx.x >> 6;
    if (lane == 0) part[wv] = kld;
    __syncthreads();
    if (threadIdx.x == 0)
        atomicAdd(&dout[0], (part[0] + part[1] + part[2] + part[3]) / (float)E);
}

// ---------------- host ----------------
extern "C" void kernel_launch(void* const* d_in, const int* in_sizes, int n_in,
                              void* d_out, int out_size, void* d_ws, size_t ws_size,
                              hipStream_t stream)
{
    const float* x   = (const float*)d_in[0];
    const int*   ei  = (const int*)d_in[1];
    const float* eps = (const float*)d_in[2];
    const float* W1  = (const float*)d_in[3];
    const float* b1  = (const float*)d_in[4];
    const float* W2  = (const float*)d_in[5];
    const float* b2  = (const float*)d_in[6];
    const float* Wl  = (const float*)d_in[7];
    const float* bl  = (const float*)d_in[8];
    float* out = (float*)d_out;
    float* ws  = (float*)d_ws;

    const int N = in_sizes[0] / DNODE;   // 10000
    const int E = in_sizes[1] / 2;       // 100000
    const int* e0 = ei;
    const int* e1 = ei + E;

    // workspace layout (float slots), total ~92 MB
    float* dinv     = ws;                                        // 16384
    float* H1s      = dinv + 16384;                              // N*512
    float* h2f      = H1s + (size_t)N * H1DIM;                   // N*256
    float* pre_raw  = h2f + (size_t)N * H2DIM;                   // E
    float* pre_low  = pre_raw + E;                               // N (pad to 16384)
    float* fend     = pre_low + 16384;
    unsigned short* XWb16 = (unsigned short*)fend;               // N*1024 bf16
    unsigned short* out1b = XWb16 + (size_t)N * NPACK;           // N*512 bf16
    unsigned short* xb    = out1b + (size_t)N * H1DIM;           // N*1280 bf16
    unsigned short* Bpt1  = xb + (size_t)N * DNODE;              // 1024*1280 bf16
    unsigned short* W2t   = Bpt1 + (size_t)NPACK * DNODE;        // 256*512 bf16
    int* hist   = (int*)(W2t + (size_t)H2DIM * H1DIM);           // N
    int* cursor = hist + N;                                      // N
    int* off    = cursor + N;                                    // N+1
    int* srcs   = off + (N + 1);                                 // E

    // 0) async zero: hist + kld accumulator
    hipMemsetAsync(hist, 0, (size_t)N * sizeof(int), stream);
    hipMemsetAsync(out, 0, sizeof(float), stream);

    // 1) CSR build + dinv
    hist_k<<<(E + 255) / 256, 256, 0, stream>>>(e1, hist, E);
    scan_dinv_k<<<1, 1024, 0, stream>>>(hist, off, cursor, dinv, N);
    fill_k<<<(E + 255) / 256, 256, 0, stream>>>(e0, e1, off, cursor, srcs, E);

    // 2) prep: x -> bf16; W1 halves -> packed B^T bf16; W2 -> B^T bf16
    cvt_x_k<<<(N * DNODE / 4 + 255) / 256, 256, 0, stream>>>(x, xb, N * DNODE);
    transpose_cvt_k<<<dim3(H1DIM / 32, DNODE / 32), 256, 0, stream>>>(W1, Bpt1, H1DIM, DNODE);
    transpose_cvt_k<<<dim3(H1DIM / 32, DNODE / 32), 256, 0, stream>>>(
        W1 + (size_t)DNODE * H1DIM, Bpt1 + (size_t)H1DIM * DNODE, H1DIM, DNODE);
    transpose_cvt_k<<<dim3(H2DIM / 32, H1DIM / 32), 256, 0, stream>>>(W2, W2t, H2DIM, H1DIM);

    // 3) GEMM1: XWb16[N][1024] = xb @ [W1top | W1bot]  (bf16 out, XCD swizzle)
    {
        const int nwg = 4 * ((N + BM - 1) / BM);
        gemm_u_k<0><<<nwg, 512, 0, stream>>>(
            xb, Bpt1, XWb16, nullptr, nullptr, b1, b2, Wl, e0, e1,
            nullptr, nullptr, N, DNODE, 0, nwg);
    }

    // 4) layer-1 message rows + CSR aggregation (post-relu bf16 out1)
    build1_k<<<N, 256, 0, stream>>>(XWb16, dinv, e0, e1, H1s);
    agg1_k<<<N, 256, 0, stream>>>(H1s, off, srcs, b1, dinv, out1b);

    // 5) GEMM2: h2 rows<N (fp32) + fused pre_raw for rows>=N
    {
        const int nwg = (E + BM - 1) / BM;
        gemm_u_k<1><<<nwg, 512, 0, stream>>>(
            nullptr, W2t, nullptr, out1b, XWb16, b1, b2, Wl, e0, e1,
            h2f, pre_raw, E, H1DIM, N, nwg);
    }

    // 6) layer-2 CSR aggregation fused with Wl dot -> pre_low
    agg2_k<<<N, 256, 0, stream>>>(h2f, off, srcs, b2, Wl, dinv, pre_low);

    // 7) final gumbel-sigmoid + mask + kld
    final2_k<<<(E + 255) / 256, 256, 0, stream>>>(pre_low, pre_raw, bl, eps, out, E, N);
}

// Round 5
// 218.758 us; speedup vs baseline: 1.1762x; 1.1762x over previous
//
#include <hip/hip_runtime.h>
#include <cstdint>
#include <cstddef>

#define H1DIM 512
#define H2DIM 256
#define DNODE 1280
#define NPACK 1024   // GEMM1 packed output width (XWt | XWb), bf16
#define APAD  40     // LDS row stride in ushorts: 80B keeps b128 reads 16B-aligned, 2-way banks

typedef __attribute__((ext_vector_type(8))) short short8v;
typedef __attribute__((ext_vector_type(4))) float f32x4;
typedef __attribute__((ext_vector_type(4))) unsigned short us4;

__device__ __forceinline__ unsigned short f2bf(float f) {
    unsigned int u = __builtin_bit_cast(unsigned int, f);
    u += 0x7fffu + ((u >> 16) & 1u);   // RNE
    return (unsigned short)(u >> 16);
}
__device__ __forceinline__ float bf2f(unsigned short h) {
    unsigned int u = ((unsigned int)h) << 16;
    return __builtin_bit_cast(float, u);
}

// ---------------- CSR build ----------------
__global__ void hist_k(const int* __restrict__ e1, int* __restrict__ hist, int E) {
    int e = blockIdx.x * 256 + threadIdx.x;
    if (e < E) atomicAdd(&hist[e1[e]], 1);
}
__global__ __launch_bounds__(1024) void scan_dinv_k(
    const int* __restrict__ hist, int* __restrict__ off, int* __restrict__ cursor,
    float* __restrict__ dinv, int N)
{
    __shared__ int part[1024];
    const int t = threadIdx.x;
    const int per = (N + 1023) / 1024;
    const int base = t * per;
    int s = 0;
    for (int i = 0; i < per; ++i) { int b = base + i; if (b < N) s += hist[b]; }
    part[t] = s;
    __syncthreads();
    for (int d = 1; d < 1024; d <<= 1) {
        int v = (t >= d) ? part[t - d] : 0;
        __syncthreads();
        part[t] += v;
        __syncthreads();
    }
    int run = (t == 0) ? 0 : part[t - 1];
    for (int i = 0; i < per; ++i) {
        int b = base + i;
        if (b < N) {
            int h = hist[b];
            off[b] = run;
            run += h;
            cursor[b] = 0;
            dinv[b] = rsqrtf(1.0f + (float)h);
        }
    }
    if (t == 1023) off[N] = run;
}
__global__ void fill_k(const int* __restrict__ e0, const int* __restrict__ e1,
                       const int* __restrict__ off, int* __restrict__ cursor,
                       int* __restrict__ srcs, int E) {
    int e = blockIdx.x * 256 + threadIdx.x;
    if (e < E) {
        int t = e1[e];
        int p = off[t] + atomicAdd(&cursor[t], 1);
        srcs[p] = e0[e];
    }
}

// ---------------- prep ----------------
__global__ void cvt_x_k(const float* __restrict__ src, unsigned short* __restrict__ dst, int n) {
    int i = blockIdx.x * 256 + threadIdx.x;
    if (i * 4 < n) {
        f32x4 v = *reinterpret_cast<const f32x4*>(src + (size_t)i * 4);
        us4 o;
        o[0] = f2bf(v.x); o[1] = f2bf(v.y); o[2] = f2bf(v.z); o[3] = f2bf(v.w);
        *reinterpret_cast<us4*>(dst + (size_t)i * 4) = o;
    }
}

__global__ __launch_bounds__(256) void transpose_cvt_k(
    const float* __restrict__ src, unsigned short* __restrict__ dst, int ldsrc, int lddst)
{
    __shared__ float tile[32][33];
    const int c0 = blockIdx.x * 32;
    const int r0 = blockIdx.y * 32;
    const int tx = threadIdx.x & 31;
    const int ty = threadIdx.x >> 5;
#pragma unroll
    for (int rr = ty; rr < 32; rr += 8)
        tile[rr][tx] = src[(size_t)(r0 + rr) * ldsrc + c0 + tx];
    __syncthreads();
#pragma unroll
    for (int rr = ty; rr < 32; rr += 8)
        dst[(size_t)(c0 + rr) * lddst + r0 + tx] = f2bf(tile[tx][rr]);
}

// ---------------- unified bf16 MFMA GEMM, tile 128x256, BK=32, 512 thr (8 waves 2Mx4N) ----
// Double-buffered LDS ([row][APAD] layout, 2-way-conflict reads), ONE barrier per K-step.
// MODE 0 (GEMM1): A = Ab bf16 [M][K]; C = Cb bf16 [M][NPACK], 4 n-tiles, XCD swizzle.
// MODE 1 (GEMM2): K=512, single n-tile (256). A row gm:
//     gm < Nn : out1b[gm] (post-relu bf16)
//     else    : relu(b1 + XWb16[e0[gm]][0:512] + XWb16[e1[gm]][512:1024])  (bf16 gather)
//   Outputs: h2b rows < Nn (bf16), pre_raw[gm] = relu(h2+b2)·Wl for gm >= Nn.
template <int MODE>
__global__ __launch_bounds__(512) void gemm_u_k(
    const unsigned short* __restrict__ Ab,
    const unsigned short* __restrict__ Bt,
    unsigned short* __restrict__ Cb,
    const unsigned short* __restrict__ out1b,
    const unsigned short* __restrict__ XWb16,
    const float* __restrict__ b1,
    const float* __restrict__ b2,
    const float* __restrict__ Wl,
    const int* __restrict__ e0, const int* __restrict__ e1,
    unsigned short* __restrict__ h2b, float* __restrict__ pre_raw,
    int M, int K, int Nn, int nwg)
{
    __shared__ unsigned short As[2][128 * APAD];
    __shared__ unsigned short Bs[2][256 * APAD];
    __shared__ float b1s[H1DIM];
    __shared__ float b2s[H2DIM];
    __shared__ float wls[H2DIM];
    __shared__ float preacc[128];

    const int tid  = threadIdx.x;
    const int lane = tid & 63;
    const int w    = tid >> 6;
    const int wm   = w >> 2, wn = w & 3;

    int mb, n0;
    if (MODE == 0) {
        // bijective XCD swizzle (m204): consecutive logical tiles land on one XCD
        const int q = nwg >> 3, r = nwg & 7;
        const int xcd = blockIdx.x & 7;
        const int base = (xcd < r) ? xcd * (q + 1) : r * (q + 1) + (xcd - r) * q;
        const int wg = base + (blockIdx.x >> 3);
        mb = wg >> 2;             // n fastest: 4 n-tiles share A rows in L2
        n0 = (wg & 3) << 8;
    } else {
        mb = blockIdx.x;
        n0 = 0;
    }
    const int m0 = mb * 128;

    if (MODE == 1) {
        if (tid < 128) preacc[tid] = 0.f;
        if (tid < 256) { b2s[tid] = b2[tid]; wls[tid] = Wl[tid]; }
        b1s[tid] = b1[tid];
    }

    // staging: A 128x32 (8 bf16/thr), B 256x32 (16 bf16/thr)
    const int sa_r = tid >> 2, sa_k = (tid & 3) << 3;
    const int sb_r = tid >> 1, sb_k = (tid & 1) << 4;
    const int gma  = m0 + sa_r;
    const bool aval = (gma < M);

    const unsigned short* bsrc = Bt + (size_t)(n0 + sb_r) * K + sb_k;
    const unsigned short* s1 = nullptr;
    const unsigned short* s2 = nullptr;
    bool dual = false;
    if (MODE == 0) {
        if (aval) s1 = Ab + (size_t)gma * K + sa_k;
    } else if (aval) {
        if (gma < Nn) {
            s1 = out1b + (size_t)gma * H1DIM + sa_k;
        } else {
            s1 = XWb16 + (size_t)e0[gma] * NPACK + sa_k;
            s2 = XWb16 + (size_t)e1[gma] * NPACK + H1DIM + sa_k;
            dual = true;
        }
    }
    if (MODE == 1) __syncthreads();   // b1s/b2s/wls/preacc ready

    f32x4 acc[4][4];
#pragma unroll
    for (int i = 0; i < 4; ++i)
#pragma unroll
        for (int j = 0; j < 4; ++j) acc[i][j] = f32x4{0.f, 0.f, 0.f, 0.f};

    short8v ab1, ab2, bb0, bb1;

    auto load_tile = [&](int k0) {
        bb0 = *reinterpret_cast<const short8v*>(bsrc + k0);
        bb1 = *reinterpret_cast<const short8v*>(bsrc + k0 + 8);
        if (aval) {
            ab1 = *reinterpret_cast<const short8v*>(s1 + k0);
            if (MODE == 1 && dual) ab2 = *reinterpret_cast<const short8v*>(s2 + k0);
        }
    };
    auto write_lds = [&](int buf, int k0) {
        *reinterpret_cast<short8v*>(&Bs[buf][sb_r * APAD + sb_k])     = bb0;
        *reinterpret_cast<short8v*>(&Bs[buf][sb_r * APAD + sb_k + 8]) = bb1;
        short8v av;
        if (!aval) {
            av = short8v{0,0,0,0,0,0,0,0};
        } else if (MODE == 0 || !dual) {
            av = ab1;   // bf16 passthrough (xb / out1b already converted)
        } else {
#pragma unroll
            for (int ii = 0; ii < 8; ++ii) {
                float v = bf2f((unsigned short)ab1[ii]) + bf2f((unsigned short)ab2[ii])
                        + b1s[k0 + sa_k + ii];
                v = fmaxf(v, 0.f);
                av[ii] = (short)f2bf(v);
            }
        }
        *reinterpret_cast<short8v*>(&As[buf][sa_r * APAD + sa_k]) = av;
    };

    const int arow = wm * 64 + (lane & 15);
    const int brow = wn * 64 + (lane & 15);
    const int kq   = (lane >> 4) << 3;

    load_tile(0);
    int buf = 0;
    for (int k0 = 0; k0 < K; k0 += 32) {
        write_lds(buf, k0);
        __syncthreads();                     // writes to buf visible; iter i-1 reads of buf^1 done
        if (k0 + 32 < K) load_tile(k0 + 32); // global loads overlap this step's LDS reads + MFMA

        const unsigned short* as = As[buf];
        const unsigned short* bs = Bs[buf];
        short8v af[4], bfq[4];
#pragma unroll
        for (int i = 0; i < 4; ++i)
            af[i] = *reinterpret_cast<const short8v*>(&as[(arow + i * 16) * APAD + kq]);
#pragma unroll
        for (int j = 0; j < 4; ++j)
            bfq[j] = *reinterpret_cast<const short8v*>(&bs[(brow + j * 16) * APAD + kq]);
#pragma unroll
        for (int i = 0; i < 4; ++i)
#pragma unroll
            for (int j = 0; j < 4; ++j)
                acc[i][j] = __builtin_amdgcn_mfma_f32_16x16x32_bf16(af[i], bfq[j], acc[i][j], 0, 0, 0);
        buf ^= 1;                            // next step writes other buffer: no 2nd barrier
    }

    const int crow0 = m0 + wm * 64 + ((lane >> 4) << 2);
    if (MODE == 0) {
        const int ccol = n0 + wn * 64 + (lane & 15);
#pragma unroll
        for (int i = 0; i < 4; ++i)
#pragma unroll
            for (int q = 0; q < 4; ++q) {
                const int row = crow0 + i * 16 + q;
                if (row < M) {
#pragma unroll
                    for (int j = 0; j < 4; ++j)
                        Cb[(size_t)row * NPACK + ccol + j * 16] = f2bf(acc[i][j][q]);
                }
            }
    } else {
        // fused pre = relu(h2 + b2) · Wl  (per-row scalar)
        const int cbase = wn * 64 + (lane & 15);
#pragma unroll
        for (int i = 0; i < 4; ++i)
#pragma unroll
            for (int q = 0; q < 4; ++q) {
                float v = 0.f;
#pragma unroll
                for (int j = 0; j < 4; ++j) {
                    const int c = cbase + j * 16;
                    v += fmaxf(acc[i][j][q] + b2s[c], 0.f) * wls[c];
                }
                v += __shfl_xor(v, 1, 64);
                v += __shfl_xor(v, 2, 64);
                v += __shfl_xor(v, 4, 64);
                v += __shfl_xor(v, 8, 64);
                if ((lane & 15) == 0)
                    atomicAdd(&preacc[wm * 64 + i * 16 + ((lane >> 4) << 2) + q], v);
            }
        if (m0 < Nn) {
            const int ccol = wn * 64 + (lane & 15);
#pragma unroll
            for (int i = 0; i < 4; ++i)
#pragma unroll
                for (int q = 0; q < 4; ++q) {
                    const int row = crow0 + i * 16 + q;
                    if (row < Nn) {
#pragma unroll
                        for (int j = 0; j < 4; ++j)
                            h2b[(size_t)row * H2DIM + ccol + j * 16] = f2bf(acc[i][j][q]);
                    }
                }
        }
        __syncthreads();
        if (tid < 128) {
            const int gm = m0 + tid;
            if (gm >= Nn && gm < M) pre_raw[gm] = preacc[tid];
        }
    }
}

// ---------------- layer1: H1b[r] = (XWt[e0]+XWb[e1]) * dinv[r] (bf16 in, bf16 out) ----------------
__global__ __launch_bounds__(256) void build1_k(
    const unsigned short* __restrict__ XWb16, const float* __restrict__ dinv,
    const int* __restrict__ e0, const int* __restrict__ e1,
    unsigned short* __restrict__ H1b)
{
    const int r = blockIdx.x;
    const int a = e0[r], b = e1[r];
    const float dv = dinv[r];
    const unsigned short* pt = XWb16 + (size_t)a * NPACK;
    const unsigned short* pb = XWb16 + (size_t)b * NPACK + H1DIM;
    const int j = threadIdx.x * 2;
    const unsigned ut = *reinterpret_cast<const unsigned*>(pt + j);
    const unsigned ub = *reinterpret_cast<const unsigned*>(pb + j);
    const float ox = (bf2f((unsigned short)(ut & 0xffff)) + bf2f((unsigned short)(ub & 0xffff))) * dv;
    const float oy = (bf2f((unsigned short)(ut >> 16))   + bf2f((unsigned short)(ub >> 16)))   * dv;
    const unsigned pk = (unsigned)f2bf(ox) | ((unsigned)f2bf(oy) << 16);
    *reinterpret_cast<unsigned*>(H1b + (size_t)r * H1DIM + j) = pk;
}

// ---------------- CSR aggregation layer 1 -> post-relu bf16 out1 (bf16 gather: half traffic) ----
__global__ __launch_bounds__(256) void agg1_k(
    const unsigned short* __restrict__ H1b, const int* __restrict__ off, const int* __restrict__ srcs,
    const float* __restrict__ b1, const float* __restrict__ dinv,
    unsigned short* __restrict__ out1b)
{
    const int t = blockIdx.x;
    const int j = threadIdx.x * 2;
    const int s0 = off[t], s1e = off[t + 1];
    const float dt = dinv[t];
    const unsigned u0 = *reinterpret_cast<const unsigned*>(H1b + (size_t)t * H1DIM + j);
    float ax = bf2f((unsigned short)(u0 & 0xffff));
    float ay = bf2f((unsigned short)(u0 >> 16));
    for (int i = s0; i < s1e; ++i) {
        const unsigned v = *reinterpret_cast<const unsigned*>(H1b + (size_t)srcs[i] * H1DIM + j);
        ax += bf2f((unsigned short)(v & 0xffff));
        ay += bf2f((unsigned short)(v >> 16));
    }
    const float ox = fmaxf(b1[j]     + dt * ax, 0.f);
    const float oy = fmaxf(b1[j + 1] + dt * ay, 0.f);
    const unsigned pk = (unsigned)f2bf(ox) | ((unsigned)f2bf(oy) << 16);
    *reinterpret_cast<unsigned*>(out1b + (size_t)t * H1DIM + j) = pk;
}

// ---------------- CSR aggregation layer 2 (bf16 h2), fused with Wl dot -> pre_low[t] ----------
__global__ __launch_bounds__(128) void agg2_k(
    const unsigned short* __restrict__ h2b, const int* __restrict__ off, const int* __restrict__ srcs,
    const float* __restrict__ b2, const float* __restrict__ Wl,
    const float* __restrict__ dinv, float* __restrict__ pre_low)
{
    __shared__ float part[2];
    const int t = blockIdx.x;
    const int j = threadIdx.x * 2;          // 128 threads x 2 cols, u32 loads (coalesced 512B/row)
    const int s0 = off[t], s1e = off[t + 1];
    const float dt = dinv[t];
    const unsigned u0 = *reinterpret_cast<const unsigned*>(h2b + (size_t)t * H2DIM + j);
    float ax = bf2f((unsigned short)(u0 & 0xffff)) * dt;
    float ay = bf2f((unsigned short)(u0 >> 16)) * dt;
    for (int i = s0; i < s1e; ++i) {
        const int s = srcs[i];
        const float ds = dinv[s];
        const unsigned v = *reinterpret_cast<const unsigned*>(h2b + (size_t)s * H2DIM + j);
        ax += bf2f((unsigned short)(v & 0xffff)) * ds;
        ay += bf2f((unsigned short)(v >> 16)) * ds;
    }
    float p = fmaxf(b2[j]     + dt * ax, 0.f) * Wl[j]
            + fmaxf(b2[j + 1] + dt * ay, 0.f) * Wl[j + 1];
#pragma unroll
    for (int o = 32; o; o >>= 1) p += __shfl_down(p, o, 64);
    if ((threadIdx.x & 63) == 0) part[threadIdx.x >> 6] = p;
    __syncthreads();
    if (threadIdx.x == 0) pre_low[t] = part[0] + part[1];
}

// ---------------- final: gumbel-sigmoid + mask + kld ----------------
__global__ __launch_bounds__(256) void final2_k(
    const float* __restrict__ pre_low, const float* __restrict__ pre_raw,
    const float* __restrict__ blp, const float* __restrict__ eps,
    float* __restrict__ dout, int E, int Nn)
{
    __shared__ float part[4];
    const int i = blockIdx.x * 256 + threadIdx.x;
    float kld = 0.f;
    if (i < E) {
        const float pre = ((i < Nn) ? pre_low[i] : pre_raw[i]) + blp[0];
        const float ee = eps[i];
        const float gate = logf(ee) - log1pf(-ee) + pre;
        const float m = 1.0f / (1.0f + expf(-gate));
        dout[1 + i] = m;
        const float pos = m, neg = 1.0f - m;
        kld = pos * logf(pos * 2.0f + 1e-8f) + neg * logf(neg * 2.0f + 1e-9f);
    }
#pragma unroll
    for (int o = 32; o; o >>= 1) kld += __shfl_down(kld, o, 64);
    const int lane = threadIdx.x & 63, wv = threadIdx.x >> 6;
    if (lane == 0) part[wv] = kld;
    __syncthreads();
    if (threadIdx.x == 0)
        atomicAdd(&dout[0], (part[0] + part[1] + part[2] + part[3]) / (float)E);
}

// ---------------- host ----------------
extern "C" void kernel_launch(void* const* d_in, const int* in_sizes, int n_in,
                              void* d_out, int out_size, void* d_ws, size_t ws_size,
                              hipStream_t stream)
{
    const float* x   = (const float*)d_in[0];
    const int*   ei  = (const int*)d_in[1];
    const float* eps = (const float*)d_in[2];
    const float* W1  = (const float*)d_in[3];
    const float* b1  = (const float*)d_in[4];
    const float* W2  = (const float*)d_in[5];
    const float* b2  = (const float*)d_in[6];
    const float* Wl  = (const float*)d_in[7];
    const float* bl  = (const float*)d_in[8];
    float* out = (float*)d_out;
    float* ws  = (float*)d_ws;

    const int N = in_sizes[0] / DNODE;   // 10000
    const int E = in_sizes[1] / 2;       // 100000
    const int* e0 = ei;
    const int* e1 = ei + E;

    // workspace layout
    float* dinv     = ws;                                        // 16384
    float* pre_raw  = dinv + 16384;                              // E
    float* pre_low  = pre_raw + E;                               // N (pad to 16384)
    float* fend     = pre_low + 16384;
    unsigned short* XWb16 = (unsigned short*)fend;               // N*1024 bf16
    unsigned short* out1b = XWb16 + (size_t)N * NPACK;           // N*512 bf16
    unsigned short* H1b   = out1b + (size_t)N * H1DIM;           // N*512 bf16
    unsigned short* h2b   = H1b + (size_t)N * H1DIM;             // N*256 bf16
    unsigned short* xb    = h2b + (size_t)N * H2DIM;             // N*1280 bf16
    unsigned short* Bpt1  = xb + (size_t)N * DNODE;              // 1024*1280 bf16
    unsigned short* W2t   = Bpt1 + (size_t)NPACK * DNODE;        // 256*512 bf16
    int* hist   = (int*)(W2t + (size_t)H2DIM * H1DIM);           // N
    int* cursor = hist + N;                                      // N
    int* off    = cursor + N;                                    // N+1
    int* srcs   = off + (N + 1);                                 // E

    // 0) async zero: hist + kld accumulator
    hipMemsetAsync(hist, 0, (size_t)N * sizeof(int), stream);
    hipMemsetAsync(out, 0, sizeof(float), stream);

    // 1) CSR build + dinv
    hist_k<<<(E + 255) / 256, 256, 0, stream>>>(e1, hist, E);
    scan_dinv_k<<<1, 1024, 0, stream>>>(hist, off, cursor, dinv, N);
    fill_k<<<(E + 255) / 256, 256, 0, stream>>>(e0, e1, off, cursor, srcs, E);

    // 2) prep: x -> bf16; W1 halves -> packed B^T bf16; W2 -> B^T bf16
    cvt_x_k<<<(N * DNODE / 4 + 255) / 256, 256, 0, stream>>>(x, xb, N * DNODE);
    transpose_cvt_k<<<dim3(H1DIM / 32, DNODE / 32), 256, 0, stream>>>(W1, Bpt1, H1DIM, DNODE);
    transpose_cvt_k<<<dim3(H1DIM / 32, DNODE / 32), 256, 0, stream>>>(
        W1 + (size_t)DNODE * H1DIM, Bpt1 + (size_t)H1DIM * DNODE, H1DIM, DNODE);
    transpose_cvt_k<<<dim3(H2DIM / 32, H1DIM / 32), 256, 0, stream>>>(W2, W2t, H2DIM, H1DIM);

    // 3) GEMM1: XWb16[N][1024] = xb @ [W1top | W1bot]  (bf16 out, XCD swizzle)
    {
        const int nwg = 4 * ((N + 127) / 128);
        gemm_u_k<0><<<nwg, 512, 0, stream>>>(
            xb, Bpt1, XWb16, nullptr, nullptr, b1, b2, Wl, e0, e1,
            nullptr, nullptr, N, DNODE, 0, nwg);
    }

    // 4) layer-1 message rows (bf16) + CSR aggregation (post-relu bf16 out1)
    build1_k<<<N, 256, 0, stream>>>(XWb16, dinv, e0, e1, H1b);
    agg1_k<<<N, 256, 0, stream>>>(H1b, off, srcs, b1, dinv, out1b);

    // 5) GEMM2: h2 rows<N (bf16) + fused pre_raw for rows>=N
    {
        const int nwg = (E + 127) / 128;
        gemm_u_k<1><<<nwg, 512, 0, stream>>>(
            nullptr, W2t, nullptr, out1b, XWb16, b1, b2, Wl, e0, e1,
            h2b, pre_raw, E, H1DIM, N, nwg);
    }

    // 6) layer-2 CSR aggregation (bf16 gather) fused with Wl dot -> pre_low
    agg2_k<<<N, 128, 0, stream>>>(h2b, off, srcs, b2, Wl, dinv, pre_low);

    // 7) final gumbel-sigmoid + mask + kld
    final2_k<<<(E + 255) / 256, 256, 0, stream>>>(pre_low, pre_raw, bl, eps, out, E, N);
}